// Round 7
// baseline (307.544 us; speedup 1.0000x reference)
//
#include <hip/hip_runtime.h>

#define EPB     64
#define E_TOTAL 262144
#define NPROBE  100000
#define N_ATOMS 20000
#define NTAB    2048         // lerp intervals over dist in [0,4)

// LDS layout (main): A2/G region = 17,408 B + misc -> 8 blocks/CU
#define ASTR   136           // row stride shorts: 272 B = 16 B * 17 -> 2-way (free) banks
#define A2_O   0
#define LDS_SH 8704

// workspace layout (byte offsets)
#define WS1_O  0             // shorts: w_s1^T bf16 128x384
#define WS2_O  49152         // shorts: w_s2^T bf16 128x128
#define WO1_O  65536         // shorts: w_o1^T bf16 64x128
#define WT_TOT 73728         // shorts
#define PQ_B   147456        // PQ[a][512] bf16 (20.48 MB)
#define WTI_B  20627456      // uint wtabI[NTAB][128] interleaved bf16 pairs (1.0 MB)
#define CNT_B  21676032      // int cnt[20000]
#define CUR_B  21756032      // int cursor[20000]
#define ED_B   21836032      // float4 ediff[E_TOTAL] = {dx,dy,dz, (atom<<17)|probe} (4 MB)
// total ~25.8 MB

// prep1 linear-region extents
#define L_WT_OFF   NPROBE                  // 100000
#define L_HIST_OFF (NPROBE + WT_TOT)       // 173728
#define L_TOT      (L_HIST_OFF + E_TOTAL)  // 435872
#define LINB       ((L_TOT + 255) / 256)   // 1703

typedef __attribute__((ext_vector_type(8))) short          short8;
typedef __attribute__((ext_vector_type(8))) unsigned short ushort8;
typedef __attribute__((ext_vector_type(4))) float          floatx4;

#define MFMA16(a, b, c) __builtin_amdgcn_mfma_f32_16x16x32_bf16((a), (b), (c), 0, 0, 0)

__device__ __forceinline__ unsigned short f2bfu(float x) {   // RNE
    unsigned u = __builtin_bit_cast(unsigned, x);
    u = (u + 0x7FFFu + ((u >> 16) & 1u)) >> 16;
    return (unsigned short)u;
}
__device__ __forceinline__ unsigned pk2(float lo, float hi) {   // {bf16(hi)|bf16(lo)} trunc
    return __builtin_amdgcn_perm(__builtin_bit_cast(unsigned, hi),
                                 __builtin_bit_cast(unsigned, lo), 0x07060302u);
}
__device__ __forceinline__ float bf2f(unsigned short u) {
    return __builtin_bit_cast(float, ((unsigned)u) << 16);
}
__device__ __forceinline__ float silu_f(float x) { return x / (1.0f + __expf(-x)); }

struct F8 { float v[8]; };
__device__ __forceinline__ F8 ld8(const float* __restrict__ p) {
    F8 r;
    const float4 a = *(const float4*)p;
    const float4 b = *(const float4*)(p + 4);
    r.v[0] = a.x; r.v[1] = a.y; r.v[2] = a.z; r.v[3] = a.w;
    r.v[4] = b.x; r.v[5] = b.y; r.v[6] = b.z; r.v[7] = b.w;
    return r;
}

// ---------- prep1: out-init + wt transpose + histogram + packed W-table ----------
// blocks [0, LINB): linear index work; blocks [LINB, LINB+NTAB): table row pair r,r+1.
__global__ __launch_bounds__(256) void cfr_prep1(
    const float* __restrict__ w_s1, const float* __restrict__ w_s2,
    const float* __restrict__ w_o1,
    const float* __restrict__ w_f1, const float* __restrict__ b_f1,
    const float* __restrict__ w_f2, const float* __restrict__ b_f2,
    const int* __restrict__ atom_idx,
    const float* __restrict__ fb, float* __restrict__ out,
    unsigned short* __restrict__ wt, int* __restrict__ cnt,
    unsigned* __restrict__ wtabI)
{
    __shared__ float ep[2][32];
    __shared__ float f1s[2][128];
    __shared__ float ws[2][128];
    const int t = threadIdx.x;

    if (blockIdx.x < LINB) {
        int i = blockIdx.x * 256 + t;
        if (i < NPROBE) {
            out[i] = fb[0];
        } else if (i < L_HIST_OFF) {
            int j = i - L_WT_OFF;
            float v;
            if (j < WS2_O)      { int n = j / 384, k = j - n * 384;           v = w_s1[k * 128 + n]; }
            else if (j < WO1_O) { int m = j - WS2_O, n = m >> 7, k = m & 127; v = w_s2[k * 128 + n]; }
            else                { int m = j - WO1_O, n = m >> 7, k = m & 127; v = w_o1[k * 64 + n]; }
            wt[j] = f2bfu(v);
        } else if (i < L_TOT) {
            atomicAdd(&cnt[atom_idx[i - L_HIST_OFF]], 1);
        }
        return;
    }

    // table block: rows r (half 0) and r+1 (half 1)
    const int r    = blockIdx.x - LINB;         // 0..NTAB-1
    const int half = t >> 7;                    // 0 / 1
    const int c    = t & 127;
    float d = fmaxf((r + half) * (4.0f / NTAB), 1e-4f);
    if (c < 32) ep[half][c] = sinf(d * (c + 1) * 0.7853981633974483f) / d;
    __syncthreads();
    float f1 = b_f1[c];
#pragma unroll
    for (int k = 0; k < 32; ++k) f1 = fmaf(ep[half][k], w_f1[k * 128 + c], f1);
    f1s[half][c] = silu_f(f1);
    __syncthreads();
    float w = b_f2[c];
#pragma unroll 4
    for (int k = 0; k < 128; ++k) w = fmaf(f1s[half][k], w_f2[k * 128 + c], w);
    ws[half][c] = w;
    __syncthreads();
    if (half == 0)
        wtabI[r * 128 + c] = ((unsigned)f2bfu(ws[1][c]) << 16) | (unsigned)f2bfu(ws[0][c]);
}

// ---------- prep2: block 0 = exclusive scan; blocks 1.. = per-atom PQ build ----------
__global__ __launch_bounds__(256, 3) void cfr_prep2(
    const float* __restrict__ S, const float* __restrict__ V,
    const float* __restrict__ b_s1,
    const unsigned short* __restrict__ wt, unsigned short* __restrict__ pq,
    const int* __restrict__ cnt, int* __restrict__ cur)
{
    __shared__ __align__(16) unsigned short lds[21504];   // bufH 8448 | bufV 13056 (43 KB)
    unsigned short* bufH = lds;                // [32][264]
    unsigned short* bufV = lds + 8448;         // [96][136]
    const int t = threadIdx.x;

    if (blockIdx.x == 0) {                     // ---- scan: 79 bins/thread + 256-scan ----
        int* part = (int*)lds;
        const int base = t * 79;
        int loc[79]; int s = 0;
#pragma unroll 1
        for (int i = 0; i < 79; ++i) {
            int v = (base + i < N_ATOMS) ? cnt[base + i] : 0;
            loc[i] = s; s += v;
        }
        part[t] = s;
        __syncthreads();
        for (int d = 1; d < 256; d <<= 1) {
            int v = (t >= d) ? part[t - d] : 0;
            __syncthreads();
            part[t] += v;
            __syncthreads();
        }
        int pre = (t == 0) ? 0 : part[t - 1];
#pragma unroll 1
        for (int i = 0; i < 79; ++i)
            if (base + i < N_ATOMS) cur[base + i] = pre + loc[i];
        return;
    }

    const int a0   = (blockIdx.x - 1) * 32;
    const int wave = t >> 6;
    const int lane = t & 63;
    const int q    = lane >> 4;
    const int c16  = lane & 15;

#pragma unroll
    for (int it = 0; it < 2; ++it) {
        int idx = it * 256 + t;
        int al = idx >> 4, f8 = (idx & 15) * 8;
        int a = a0 + al;
        ushort8 sS, sN, s0, s1, s2;
        if (a < N_ATOMS) {
            F8 s  = ld8(S + a * 128 + f8);
            F8 v0 = ld8(V + a * 384 + f8);
            F8 v1 = ld8(V + a * 384 + 128 + f8);
            F8 v2 = ld8(V + a * 384 + 256 + f8);
#pragma unroll
            for (int j = 0; j < 8; ++j) {
                sS[j] = f2bfu(s.v[j]);
                sN[j] = f2bfu(sqrtf(v0.v[j]*v0.v[j] + v1.v[j]*v1.v[j] + v2.v[j]*v2.v[j] + 1e-8f));
                s0[j] = f2bfu(v0.v[j]);
                s1[j] = f2bfu(v1.v[j]);
                s2[j] = f2bfu(v2.v[j]);
            }
        } else {
#pragma unroll
            for (int j = 0; j < 8; ++j) { sS[j]=0; sN[j]=0; s0[j]=0; s1[j]=0; s2[j]=0; }
        }
        *(ushort8*)&bufH[al * 264 + f8]        = sS;
        *(ushort8*)&bufH[al * 264 + 128 + f8]  = sN;
        *(ushort8*)&bufV[al * 136 + f8]        = s0;
        *(ushort8*)&bufV[(32 + al) * 136 + f8] = s1;
        *(ushort8*)&bufV[(64 + al) * 136 + f8] = s2;
    }
    __syncthreads();

    const floatx4 zero4 = {0.f, 0.f, 0.f, 0.f};
    float bs1c[2];
#pragma unroll
    for (int ni = 0; ni < 2; ++ni) bs1c[ni] = b_s1[wave * 32 + ni * 16 + c16];

    {   // P = [S|n] @ w_s1[0:256] + b_s1
        floatx4 pacc[2][2];
#pragma unroll
        for (int mi = 0; mi < 2; ++mi) { pacc[mi][0] = zero4; pacc[mi][1] = zero4; }
#pragma unroll
        for (int kk = 0; kk < 8; ++kk) {
            short8 bfr[2], af[2];
#pragma unroll
            for (int ni = 0; ni < 2; ++ni) {
                int n = wave * 32 + ni * 16 + c16;
                bfr[ni] = *(const short8*)&wt[WS1_O + n * 384 + kk * 32 + q * 8];
            }
#pragma unroll
            for (int mi = 0; mi < 2; ++mi)
                af[mi] = *(const short8*)&bufH[(mi * 16 + c16) * 264 + kk * 32 + q * 8];
#pragma unroll
            for (int mi = 0; mi < 2; ++mi)
#pragma unroll
                for (int ni = 0; ni < 2; ++ni)
                    pacc[mi][ni] = MFMA16(af[mi], bfr[ni], pacc[mi][ni]);
        }
#pragma unroll
        for (int mi = 0; mi < 2; ++mi)
#pragma unroll
            for (int r = 0; r < 4; ++r) {
                int a = a0 + mi * 16 + q * 4 + r;
                if (a < N_ATOMS)
#pragma unroll
                    for (int ni = 0; ni < 2; ++ni) {
                        int col = wave * 32 + ni * 16 + c16;
                        pq[a * 512 + col] = f2bfu(pacc[mi][ni][r] + bs1c[ni]);
                    }
            }
    }

    short8 bq[4][2];
#pragma unroll
    for (int kk = 0; kk < 4; ++kk)
#pragma unroll
        for (int ni = 0; ni < 2; ++ni) {
            int n = wave * 32 + ni * 16 + c16;
            bq[kk][ni] = *(const short8*)&wt[WS1_O + n * 384 + 256 + kk * 32 + q * 8];
        }
#pragma unroll
    for (int d = 0; d < 3; ++d) {
        floatx4 qacc[2][2];
#pragma unroll
        for (int mi = 0; mi < 2; ++mi) { qacc[mi][0] = zero4; qacc[mi][1] = zero4; }
#pragma unroll
        for (int kk = 0; kk < 4; ++kk) {
            short8 af[2];
#pragma unroll
            for (int mi = 0; mi < 2; ++mi)
                af[mi] = *(const short8*)&bufV[(d * 32 + mi * 16 + c16) * 136 + kk * 32 + q * 8];
#pragma unroll
            for (int mi = 0; mi < 2; ++mi)
#pragma unroll
                for (int ni = 0; ni < 2; ++ni)
                    qacc[mi][ni] = MFMA16(af[mi], bq[kk][ni], qacc[mi][ni]);
        }
#pragma unroll
        for (int mi = 0; mi < 2; ++mi)
#pragma unroll
            for (int r = 0; r < 4; ++r) {
                int a = a0 + mi * 16 + q * 4 + r;
                if (a < N_ATOMS)
#pragma unroll
                    for (int ni = 0; ni < 2; ++ni) {
                        int col = wave * 32 + ni * 16 + c16;
                        pq[a * 512 + (1 + d) * 128 + col] = f2bfu(qacc[mi][ni][r]);
                    }
            }
    }
}

// ---------- prep3: scatter edges into atom-sorted order; pack (atom<<17)|probe ----------
__global__ void cfr_scatter(const int* __restrict__ atom_idx, const int* __restrict__ probe_idx,
                            const float* __restrict__ diff,
                            int* __restrict__ cur, float4* __restrict__ ediff) {
    int e = blockIdx.x * 256 + threadIdx.x;
    if (e >= E_TOTAL) return;
    int a = atom_idx[e];
    int pos = atomicAdd(&cur[a], 1);
    float4 ed;
    ed.x = diff[e * 3 + 0]; ed.y = diff[e * 3 + 1]; ed.z = diff[e * 3 + 2];
    ed.w = __uint_as_float(((unsigned)a << 17) | (unsigned)probe_idx[e]);
    ediff[pos] = ed;
}

__global__ __launch_bounds__(256, 8) void cfr_main(
    const float4* __restrict__ ediff,
    const unsigned short* __restrict__ wt, const unsigned short* __restrict__ pq,
    const unsigned* __restrict__ wtabI,
    const float* __restrict__ g_ln, const float* __restrict__ b_ln,
    const float* __restrict__ b_s2, const float* __restrict__ b_o1,
    const float* __restrict__ w_o2, const float* __restrict__ b_o2,
    float* __restrict__ out)
{
    __shared__ __align__(16) unsigned short LDSu[LDS_SH];   // A2, then G
    __shared__ float df[EPB];
    __shared__ int   probe_s[EPB];
    __shared__ float mpart[EPB * 4];

    const int t    = threadIdx.x;
    const int e0   = blockIdx.x * EPB;
    const int wave = t >> 6;
    const int lane = t & 63;
    const int q    = lane >> 4;
    const int c16  = lane & 15;
    const floatx4 zero4 = {0.f, 0.f, 0.f, 0.f};

    const int el = t >> 2;
    const int c0 = (t & 3) * 32;

    // ---------- phase 1: U = P + r.Q -> LN -> SiLU -> A2 ----------
    {
        float4 ed = ediff[e0 + el];
        unsigned key = __float_as_uint(ed.w);
        const int a = (int)(key >> 17);
        float sq = ed.x * ed.x + ed.y * ed.y + ed.z * ed.z;
        float dist = sqrtf(sq);
        float rinv = rsqrtf(sq + 1e-8f);
        float rx = ed.x * rinv, ry = ed.y * rinv, rz = ed.z * rinv;
        if ((t & 3) == 0) { df[el] = dist; probe_s[el] = (int)(key & 0x1FFFFu); }

        const ushort8* pqr = (const ushort8*)(pq + a * 512 + c0);
        float u[32];
#pragma unroll
        for (int g = 0; g < 4; ++g) {
            ushort8 v = pqr[g];            // P
#pragma unroll
            for (int j = 0; j < 8; ++j) u[g * 8 + j] = bf2f(v[j]);
        }
#pragma unroll
        for (int g = 0; g < 4; ++g) {
            ushort8 v = pqr[16 + g];       // Q0
#pragma unroll
            for (int j = 0; j < 8; ++j) u[g * 8 + j] = fmaf(bf2f(v[j]), rx, u[g * 8 + j]);
        }
#pragma unroll
        for (int g = 0; g < 4; ++g) {
            ushort8 v = pqr[32 + g];       // Q1
#pragma unroll
            for (int j = 0; j < 8; ++j) u[g * 8 + j] = fmaf(bf2f(v[j]), ry, u[g * 8 + j]);
        }
#pragma unroll
        for (int g = 0; g < 4; ++g) {
            ushort8 v = pqr[48 + g];       // Q2
#pragma unroll
            for (int j = 0; j < 8; ++j) u[g * 8 + j] = fmaf(bf2f(v[j]), rz, u[g * 8 + j]);
        }
        float s = 0.f, s2 = 0.f;
#pragma unroll
        for (int j = 0; j < 32; ++j) { s += u[j]; s2 = fmaf(u[j], u[j], s2); }
        s  += __shfl_xor(s, 1);  s  += __shfl_xor(s, 2);
        s2 += __shfl_xor(s2, 1); s2 += __shfl_xor(s2, 2);
        float mu = s * (1.f / 128.f);
        float rstd = rsqrtf(s2 * (1.f / 128.f) - mu * mu + 1e-5f);
        const float4* gp = (const float4*)(g_ln + c0);
        const float4* bp = (const float4*)(b_ln + c0);
        unsigned pko[16];
#pragma unroll
        for (int g4 = 0; g4 < 8; ++g4) {
            float4 gg = gp[g4], bb = bp[g4];
            float y0 = silu_f((u[g4 * 4 + 0] - mu) * rstd * gg.x + bb.x);
            float y1 = silu_f((u[g4 * 4 + 1] - mu) * rstd * gg.y + bb.y);
            float y2 = silu_f((u[g4 * 4 + 2] - mu) * rstd * gg.z + bb.z);
            float y3 = silu_f((u[g4 * 4 + 3] - mu) * rstd * gg.w + bb.w);
            pko[g4 * 2 + 0] = pk2(y0, y1);
            pko[g4 * 2 + 1] = pk2(y2, y3);
        }
        uint4* dst = (uint4*)&LDSu[A2_O + el * ASTR + c0];
        dst[0] = make_uint4(pko[0], pko[1], pko[2], pko[3]);
        dst[1] = make_uint4(pko[4], pko[5], pko[6], pko[7]);
        dst[2] = make_uint4(pko[8], pko[9], pko[10], pko[11]);
        dst[3] = make_uint4(pko[12], pko[13], pko[14], pko[15]);
    }
    __syncthreads();   // A2 ready

    // ---------- mm2: S = A2 @ w_s2 + b_s2, then G = S ⊙ W(dist) in C-layout ----------
    {
        floatx4 sacc[4][2];
#pragma unroll
        for (int mi = 0; mi < 4; ++mi) { sacc[mi][0] = zero4; sacc[mi][1] = zero4; }
#pragma unroll
        for (int kk = 0; kk < 4; ++kk) {
            short8 a2f[4], b2[2];
#pragma unroll
            for (int ni = 0; ni < 2; ++ni) {
                int n = wave * 32 + ni * 16 + c16;
                b2[ni] = *(const short8*)&wt[WS2_O + n * 128 + kk * 32 + q * 8];
            }
#pragma unroll
            for (int mi = 0; mi < 4; ++mi)
                a2f[mi] = *(const short8*)&LDSu[A2_O + (mi * 16 + c16) * ASTR + kk * 32 + q * 8];
#pragma unroll
            for (int mi = 0; mi < 4; ++mi)
#pragma unroll
                for (int ni = 0; ni < 2; ++ni)
                    sacc[mi][ni] = MFMA16(a2f[mi], b2[ni], sacc[mi][ni]);
        }
        __syncthreads();   // all A2 reads done; region becomes G

        float bs2c[2];
#pragma unroll
        for (int ni = 0; ni < 2; ++ni) bs2c[ni] = b_s2[wave * 32 + ni * 16 + c16];
#pragma unroll
        for (int mi = 0; mi < 4; ++mi) {
#pragma unroll
            for (int r = 0; r < 4; ++r) {
                int row = mi * 16 + q * 4 + r;
                float f  = fminf(df[row] * (NTAB / 4.0f), NTAB - 1.01f);
                float fi = floorf(f);
                int   i0 = (int)fi;
                float fr = f - fi;
                const unsigned* wrow = wtabI + i0 * 128;
#pragma unroll
                for (int ni = 0; ni < 2; ++ni) {
                    int col = wave * 32 + ni * 16 + c16;
                    unsigned wp = wrow[col];
                    float w0 = __builtin_bit_cast(float, wp << 16);
                    float w1 = __builtin_bit_cast(float, wp & 0xffff0000u);
                    float wv = fmaf(fr, w1 - w0, w0);
                    float g  = (sacc[mi][ni][r] + bs2c[ni]) * wv;
                    LDSu[A2_O + row * ASTR + col] =
                        (unsigned short)(__builtin_bit_cast(unsigned, g) >> 16);
                }
            }
        }
    }
    __syncthreads();   // G ready

    // ---------- head: O1 = G @ w_o1 ; m = silu(O1) @ w_o2 ----------
    {
        const int n2 = wave * 16 + c16;
        floatx4 oacc[4];
#pragma unroll
        for (int mi = 0; mi < 4; ++mi) oacc[mi] = zero4;
#pragma unroll
        for (int kk = 0; kk < 4; ++kk) {
            short8 bfr = *(const short8*)&wt[WO1_O + n2 * 128 + kk * 32 + q * 8];
#pragma unroll
            for (int mi = 0; mi < 4; ++mi) {
                short8 af = *(const short8*)&LDSu[A2_O + (mi * 16 + c16) * ASTR + kk * 32 + q * 8];
                oacc[mi] = MFMA16(af, bfr, oacc[mi]);
            }
        }
        float bo1c = b_o1[n2], wo2c = w_o2[n2];
#pragma unroll
        for (int mi = 0; mi < 4; ++mi)
#pragma unroll
            for (int r = 0; r < 4; ++r) {
                float s = silu_f(oacc[mi][r] + bo1c) * wo2c;
#pragma unroll
                for (int d = 1; d < 16; d <<= 1) s += __shfl_xor(s, d, 64);
                if (c16 == 0) mpart[(mi * 16 + q * 4 + r) * 4 + wave] = s;
            }
    }
    __syncthreads();

    // ---------- envelope + scatter-add ----------
    if (t < EPB) {
        float m = mpart[t * 4 + 0] + mpart[t * 4 + 1] + mpart[t * 4 + 2] + mpart[t * 4 + 3] + b_o2[0];
        float dd = df[t];
        float x  = dd * 0.25f;
        float x2 = x * x, x4 = x2 * x2;
        float x5 = x4 * x, x6 = x5 * x, x7 = x6 * x;
        float env = 1.0f - 21.0f * x5 + 35.0f * x6 - 15.0f * x7;
        env = (dd < 4.0f) ? env : 0.0f;
        float mw = m * env;
        if (mw != 0.f) unsafeAtomicAdd(&out[probe_s[t]], mw);
    }
}

extern "C" void kernel_launch(void* const* d_in, const int* in_sizes, int n_in,
                              void* d_out, int out_size, void* d_ws, size_t ws_size,
                              hipStream_t stream) {
    const float* diff    = (const float*)d_in[0];
    const float* S_JK    = (const float*)d_in[1];
    const float* V_JK    = (const float*)d_in[2];
    const int*   atom_i  = (const int*)d_in[3];
    const int*   probe_i = (const int*)d_in[4];
    const float* w_s1 = (const float*)d_in[6];
    const float* b_s1 = (const float*)d_in[7];
    const float* g_ln = (const float*)d_in[8];
    const float* b_ln = (const float*)d_in[9];
    const float* w_s2 = (const float*)d_in[10];
    const float* b_s2 = (const float*)d_in[11];
    const float* w_f1 = (const float*)d_in[12];
    const float* b_f1 = (const float*)d_in[13];
    const float* w_f2 = (const float*)d_in[14];
    const float* b_f2 = (const float*)d_in[15];
    const float* w_o1 = (const float*)d_in[16];
    const float* b_o1 = (const float*)d_in[17];
    const float* w_o2 = (const float*)d_in[18];
    const float* b_o2 = (const float*)d_in[19];
    const float* fbias = (const float*)d_in[20];
    float* out = (float*)d_out;

    char* ws = (char*)d_ws;
    unsigned short* wt    = (unsigned short*)ws;
    unsigned short* pqp   = (unsigned short*)(ws + PQ_B);
    unsigned*       wtabI = (unsigned*)(ws + WTI_B);
    int*            cnt   = (int*)(ws + CNT_B);
    int*            cur   = (int*)(ws + CUR_B);
    float4*         edif  = (float4*)(ws + ED_B);

    hipMemsetAsync(cnt, 0, N_ATOMS * sizeof(int), stream);
    cfr_prep1<<<LINB + NTAB, 256, 0, stream>>>(w_s1, w_s2, w_o1, w_f1, b_f1, w_f2, b_f2,
                                               atom_i, fbias, out, wt, cnt, wtabI);
    cfr_prep2<<<1 + (N_ATOMS + 31) / 32, 256, 0, stream>>>(S_JK, V_JK, b_s1, wt, pqp, cnt, cur);
    cfr_scatter<<<E_TOTAL / 256, 256, 0, stream>>>(atom_i, probe_i, diff, cur, edif);
    cfr_main<<<E_TOTAL / EPB, 256, 0, stream>>>(edif, wt, pqp, wtabI,
        g_ln, b_ln, b_s2, b_o1, w_o2, b_o2, out);
}

// Round 8
// 297.835 us; speedup vs baseline: 1.0326x; 1.0326x over previous
//
#include <hip/hip_runtime.h>

#define EPB     64
#define E_TOTAL 262144
#define NPROBE  100000
#define N_ATOMS 20000
#define NTAB    2048         // lerp intervals over dist in [0,4)

// LDS layout (main): A2/G region 17,408 B + df/probe ~0.8 KB -> 8 blocks/CU
#define ASTR   136           // row stride shorts: 272 B = 16 B * 17 -> 2-way (free) banks
#define A2_O   0
#define LDS_SH 8704

// workspace layout (byte offsets)
#define WS1_O  0             // shorts: w_s1^T bf16 128x384
#define WS2_O  49152         // shorts: w_s2^T bf16 128x128
#define WO1_O  65536         // shorts: w_o1^T bf16 64x128
#define WT_TOT 73728         // shorts
#define PQ_B   147456        // PQ[a][512] bf16 (20.48 MB)
#define WTI_B  20627456      // uint wtabI[NTAB][128] interleaved bf16 pairs (1.0 MB)
// total ~21.7 MB

// prep1 block ranges
#define L_WT_OFF   NPROBE                   // 100000
#define L_TOT      (NPROBE + WT_TOT)        // 173728
#define LIN1B      ((L_TOT + 255) / 256)    // 679
#define TABB       ((NTAB + 2) / 2)         // 1025 blocks, 2 rows each (rows 0..NTAB)

typedef __attribute__((ext_vector_type(8))) short          short8;
typedef __attribute__((ext_vector_type(8))) unsigned short ushort8;
typedef __attribute__((ext_vector_type(4))) float          floatx4;

#define MFMA16(a, b, c) __builtin_amdgcn_mfma_f32_16x16x32_bf16((a), (b), (c), 0, 0, 0)

__device__ __forceinline__ unsigned short f2bfu(float x) {   // RNE
    unsigned u = __builtin_bit_cast(unsigned, x);
    u = (u + 0x7FFFu + ((u >> 16) & 1u)) >> 16;
    return (unsigned short)u;
}
__device__ __forceinline__ unsigned pk2(float lo, float hi) {   // {bf16(hi)|bf16(lo)} trunc
    return __builtin_amdgcn_perm(__builtin_bit_cast(unsigned, hi),
                                 __builtin_bit_cast(unsigned, lo), 0x07060302u);
}
__device__ __forceinline__ float bf2f(unsigned short u) {
    return __builtin_bit_cast(float, ((unsigned)u) << 16);
}
__device__ __forceinline__ float silu_f(float x) { return x / (1.0f + __expf(-x)); }

struct F8 { float v[8]; };
__device__ __forceinline__ F8 ld8(const float* __restrict__ p) {
    F8 r;
    const float4 a = *(const float4*)p;
    const float4 b = *(const float4*)(p + 4);
    r.v[0] = a.x; r.v[1] = a.y; r.v[2] = a.z; r.v[3] = a.w;
    r.v[4] = b.x; r.v[5] = b.y; r.v[6] = b.z; r.v[7] = b.w;
    return r;
}

// ---------- prep1: out-init + wt transpose + W-table (interleaved via dual 16-bit stores) ----------
// blocks [0, LIN1B): linear work; blocks [LIN1B, LIN1B+TABB): table rows 2j, 2j+1.
__global__ __launch_bounds__(256) void cfr_prep1(
    const float* __restrict__ w_s1, const float* __restrict__ w_s2,
    const float* __restrict__ w_o1,
    const float* __restrict__ w_f1, const float* __restrict__ b_f1,
    const float* __restrict__ w_f2, const float* __restrict__ b_f2,
    const float* __restrict__ fb, float* __restrict__ out,
    unsigned short* __restrict__ wt, unsigned* __restrict__ wtabI)
{
    __shared__ float ep[2][32];
    __shared__ float f1s[2][128];
    const int t = threadIdx.x;

    if (blockIdx.x < LIN1B) {
        int i = blockIdx.x * 256 + t;
        if (i < NPROBE) {
            out[i] = fb[0];
        } else if (i < L_TOT) {
            int j = i - L_WT_OFF;
            float v;
            if (j < WS2_O)      { int n = j / 384, k = j - n * 384;           v = w_s1[k * 128 + n]; }
            else if (j < WO1_O) { int m = j - WS2_O, n = m >> 7, k = m & 127; v = w_s2[k * 128 + n]; }
            else                { int m = j - WO1_O, n = m >> 7, k = m & 127; v = w_o1[k * 64 + n]; }
            wt[j] = f2bfu(v);
        }
        return;
    }

    // table block: half 0 -> row 2j, half 1 -> row 2j+1 (each row computed once)
    const int half = t >> 7;
    const int c    = t & 127;
    const int r    = (blockIdx.x - LIN1B) * 2 + half;    // 0..NTAB (+1 spare, guarded)
    float d = fmaxf(r * (4.0f / NTAB), 1e-4f);
    if (c < 32) ep[half][c] = sinf(d * (c + 1) * 0.7853981633974483f) / d;
    __syncthreads();
    float f1 = b_f1[c];
#pragma unroll
    for (int k = 0; k < 32; ++k) f1 = fmaf(ep[half][k], w_f1[k * 128 + c], f1);
    f1s[half][c] = silu_f(f1);
    __syncthreads();
    if (r > NTAB) return;
    float w = b_f2[c];
#pragma unroll 4
    for (int k = 0; k < 128; ++k) w = fmaf(f1s[half][k], w_f2[k * 128 + c], w);
    unsigned short wb = f2bfu(w);
    unsigned short* wtabH = (unsigned short*)wtabI;
    if (r < NTAB) wtabH[(r * 128 + c) * 2] = wb;             // lo half of wtabI[r][c]
    if (r >= 1)   wtabH[((r - 1) * 128 + c) * 2 + 1] = wb;   // hi half of wtabI[r-1][c]
}

// ---------- prep2: per-atom P = [S|n]@w_s1[0:256] + b_s1 and Q_d = V_d@w_s1[256:384] ----------
__global__ __launch_bounds__(256, 3) void cfr_prep2(
    const float* __restrict__ S, const float* __restrict__ V,
    const float* __restrict__ b_s1,
    const unsigned short* __restrict__ wt, unsigned short* __restrict__ pq)
{
    __shared__ __align__(16) unsigned short bufH[32 * 264];
    __shared__ __align__(16) unsigned short bufV[96 * 136];

    const int t    = threadIdx.x;
    const int a0   = blockIdx.x * 32;
    const int wave = t >> 6;
    const int lane = t & 63;
    const int q    = lane >> 4;
    const int c16  = lane & 15;

#pragma unroll
    for (int it = 0; it < 2; ++it) {
        int idx = it * 256 + t;
        int al = idx >> 4, f8 = (idx & 15) * 8;
        int a = a0 + al;
        ushort8 sS, sN, s0, s1, s2;
        if (a < N_ATOMS) {
            F8 s  = ld8(S + a * 128 + f8);
            F8 v0 = ld8(V + a * 384 + f8);
            F8 v1 = ld8(V + a * 384 + 128 + f8);
            F8 v2 = ld8(V + a * 384 + 256 + f8);
#pragma unroll
            for (int j = 0; j < 8; ++j) {
                sS[j] = f2bfu(s.v[j]);
                sN[j] = f2bfu(sqrtf(v0.v[j]*v0.v[j] + v1.v[j]*v1.v[j] + v2.v[j]*v2.v[j] + 1e-8f));
                s0[j] = f2bfu(v0.v[j]);
                s1[j] = f2bfu(v1.v[j]);
                s2[j] = f2bfu(v2.v[j]);
            }
        } else {
#pragma unroll
            for (int j = 0; j < 8; ++j) { sS[j]=0; sN[j]=0; s0[j]=0; s1[j]=0; s2[j]=0; }
        }
        *(ushort8*)&bufH[al * 264 + f8]        = sS;
        *(ushort8*)&bufH[al * 264 + 128 + f8]  = sN;
        *(ushort8*)&bufV[al * 136 + f8]        = s0;
        *(ushort8*)&bufV[(32 + al) * 136 + f8] = s1;
        *(ushort8*)&bufV[(64 + al) * 136 + f8] = s2;
    }
    __syncthreads();

    const floatx4 zero4 = {0.f, 0.f, 0.f, 0.f};
    float bs1c[2];
#pragma unroll
    for (int ni = 0; ni < 2; ++ni) bs1c[ni] = b_s1[wave * 32 + ni * 16 + c16];

    {   // P
        floatx4 pacc[2][2];
#pragma unroll
        for (int mi = 0; mi < 2; ++mi) { pacc[mi][0] = zero4; pacc[mi][1] = zero4; }
#pragma unroll
        for (int kk = 0; kk < 8; ++kk) {
            short8 bfr[2], af[2];
#pragma unroll
            for (int ni = 0; ni < 2; ++ni) {
                int n = wave * 32 + ni * 16 + c16;
                bfr[ni] = *(const short8*)&wt[WS1_O + n * 384 + kk * 32 + q * 8];
            }
#pragma unroll
            for (int mi = 0; mi < 2; ++mi)
                af[mi] = *(const short8*)&bufH[(mi * 16 + c16) * 264 + kk * 32 + q * 8];
#pragma unroll
            for (int mi = 0; mi < 2; ++mi)
#pragma unroll
                for (int ni = 0; ni < 2; ++ni)
                    pacc[mi][ni] = MFMA16(af[mi], bfr[ni], pacc[mi][ni]);
        }
#pragma unroll
        for (int mi = 0; mi < 2; ++mi)
#pragma unroll
            for (int r = 0; r < 4; ++r) {
                int a = a0 + mi * 16 + q * 4 + r;
                if (a < N_ATOMS)
#pragma unroll
                    for (int ni = 0; ni < 2; ++ni) {
                        int col = wave * 32 + ni * 16 + c16;
                        pq[a * 512 + col] = f2bfu(pacc[mi][ni][r] + bs1c[ni]);
                    }
            }
    }

    short8 bq[4][2];
#pragma unroll
    for (int kk = 0; kk < 4; ++kk)
#pragma unroll
        for (int ni = 0; ni < 2; ++ni) {
            int n = wave * 32 + ni * 16 + c16;
            bq[kk][ni] = *(const short8*)&wt[WS1_O + n * 384 + 256 + kk * 32 + q * 8];
        }
#pragma unroll
    for (int d = 0; d < 3; ++d) {
        floatx4 qacc[2][2];
#pragma unroll
        for (int mi = 0; mi < 2; ++mi) { qacc[mi][0] = zero4; qacc[mi][1] = zero4; }
#pragma unroll
        for (int kk = 0; kk < 4; ++kk) {
            short8 af[2];
#pragma unroll
            for (int mi = 0; mi < 2; ++mi)
                af[mi] = *(const short8*)&bufV[(d * 32 + mi * 16 + c16) * 136 + kk * 32 + q * 8];
#pragma unroll
            for (int mi = 0; mi < 2; ++mi)
#pragma unroll
                for (int ni = 0; ni < 2; ++ni)
                    qacc[mi][ni] = MFMA16(af[mi], bq[kk][ni], qacc[mi][ni]);
        }
#pragma unroll
        for (int mi = 0; mi < 2; ++mi)
#pragma unroll
            for (int r = 0; r < 4; ++r) {
                int a = a0 + mi * 16 + q * 4 + r;
                if (a < N_ATOMS)
#pragma unroll
                    for (int ni = 0; ni < 2; ++ni) {
                        int col = wave * 32 + ni * 16 + c16;
                        pq[a * 512 + (1 + d) * 128 + col] = f2bfu(qacc[mi][ni][r]);
                    }
            }
    }
}

__global__ __launch_bounds__(256, 8) void cfr_main(
    const float* __restrict__ diff,
    const int* __restrict__ atom_idx, const int* __restrict__ probe_idx,
    const unsigned short* __restrict__ wt, const unsigned short* __restrict__ pq,
    const unsigned* __restrict__ wtabI,
    const float* __restrict__ g_ln, const float* __restrict__ b_ln,
    const float* __restrict__ b_s2, const float* __restrict__ b_o1,
    const float* __restrict__ w_o2, const float* __restrict__ b_o2,
    float* __restrict__ out)
{
    __shared__ __align__(16) unsigned short LDSu[LDS_SH];   // A2, then G
    __shared__ float df[EPB];
    __shared__ int   probe_s[EPB];

    const int t    = threadIdx.x;
    const int e0   = blockIdx.x * EPB;
    const int wave = t >> 6;
    const int lane = t & 63;
    const int q    = lane >> 4;
    const int c16  = lane & 15;
    const floatx4 zero4 = {0.f, 0.f, 0.f, 0.f};

    const int el = t >> 2;
    const int c0 = (t & 3) * 32;

    // ---------- phase 1: U = P + r.Q -> LN -> SiLU -> A2 ----------
    {
        const int eg = e0 + el;
        const int a  = atom_idx[eg];
        float dx = diff[eg * 3 + 0], dy = diff[eg * 3 + 1], dz = diff[eg * 3 + 2];
        float sq = dx * dx + dy * dy + dz * dz;
        float dist = sqrtf(sq);
        float rinv = rsqrtf(sq + 1e-8f);
        float rx = dx * rinv, ry = dy * rinv, rz = dz * rinv;
        if ((t & 3) == 0) { df[el] = dist; probe_s[el] = probe_idx[eg]; }

        const ushort8* pqr = (const ushort8*)(pq + a * 512 + c0);
        float u[32];
#pragma unroll
        for (int g = 0; g < 4; ++g) {
            ushort8 v = pqr[g];            // P
#pragma unroll
            for (int j = 0; j < 8; ++j) u[g * 8 + j] = bf2f(v[j]);
        }
#pragma unroll
        for (int g = 0; g < 4; ++g) {
            ushort8 v = pqr[16 + g];       // Q0
#pragma unroll
            for (int j = 0; j < 8; ++j) u[g * 8 + j] = fmaf(bf2f(v[j]), rx, u[g * 8 + j]);
        }
#pragma unroll
        for (int g = 0; g < 4; ++g) {
            ushort8 v = pqr[32 + g];       // Q1
#pragma unroll
            for (int j = 0; j < 8; ++j) u[g * 8 + j] = fmaf(bf2f(v[j]), ry, u[g * 8 + j]);
        }
#pragma unroll
        for (int g = 0; g < 4; ++g) {
            ushort8 v = pqr[48 + g];       // Q2
#pragma unroll
            for (int j = 0; j < 8; ++j) u[g * 8 + j] = fmaf(bf2f(v[j]), rz, u[g * 8 + j]);
        }
        float s = 0.f, s2 = 0.f;
#pragma unroll
        for (int j = 0; j < 32; ++j) { s += u[j]; s2 = fmaf(u[j], u[j], s2); }
        s  += __shfl_xor(s, 1);  s  += __shfl_xor(s, 2);
        s2 += __shfl_xor(s2, 1); s2 += __shfl_xor(s2, 2);
        float mu = s * (1.f / 128.f);
        float rstd = rsqrtf(s2 * (1.f / 128.f) - mu * mu + 1e-5f);
        const float4* gp = (const float4*)(g_ln + c0);
        const float4* bp = (const float4*)(b_ln + c0);
        unsigned pko[16];
#pragma unroll
        for (int g4 = 0; g4 < 8; ++g4) {
            float4 gg = gp[g4], bb = bp[g4];
            float y0 = silu_f((u[g4 * 4 + 0] - mu) * rstd * gg.x + bb.x);
            float y1 = silu_f((u[g4 * 4 + 1] - mu) * rstd * gg.y + bb.y);
            float y2 = silu_f((u[g4 * 4 + 2] - mu) * rstd * gg.z + bb.z);
            float y3 = silu_f((u[g4 * 4 + 3] - mu) * rstd * gg.w + bb.w);
            pko[g4 * 2 + 0] = pk2(y0, y1);
            pko[g4 * 2 + 1] = pk2(y2, y3);
        }
        uint4* dst = (uint4*)&LDSu[A2_O + el * ASTR + c0];
        dst[0] = make_uint4(pko[0], pko[1], pko[2], pko[3]);
        dst[1] = make_uint4(pko[4], pko[5], pko[6], pko[7]);
        dst[2] = make_uint4(pko[8], pko[9], pko[10], pko[11]);
        dst[3] = make_uint4(pko[12], pko[13], pko[14], pko[15]);
    }
    __syncthreads();   // A2 ready

    // ---------- mm2: S = A2 @ w_s2 + b_s2, then G = S ⊙ W(dist) in C-layout ----------
    {
        floatx4 sacc[4][2];
#pragma unroll
        for (int mi = 0; mi < 4; ++mi) { sacc[mi][0] = zero4; sacc[mi][1] = zero4; }
#pragma unroll
        for (int kk = 0; kk < 4; ++kk) {
            short8 a2f[4], b2[2];
#pragma unroll
            for (int ni = 0; ni < 2; ++ni) {
                int n = wave * 32 + ni * 16 + c16;
                b2[ni] = *(const short8*)&wt[WS2_O + n * 128 + kk * 32 + q * 8];
            }
#pragma unroll
            for (int mi = 0; mi < 4; ++mi)
                a2f[mi] = *(const short8*)&LDSu[A2_O + (mi * 16 + c16) * ASTR + kk * 32 + q * 8];
#pragma unroll
            for (int mi = 0; mi < 4; ++mi)
#pragma unroll
                for (int ni = 0; ni < 2; ++ni)
                    sacc[mi][ni] = MFMA16(a2f[mi], b2[ni], sacc[mi][ni]);
        }
        __syncthreads();   // all A2 reads done; region becomes G

        float bs2c[2];
#pragma unroll
        for (int ni = 0; ni < 2; ++ni) bs2c[ni] = b_s2[wave * 32 + ni * 16 + c16];
#pragma unroll
        for (int mi = 0; mi < 4; ++mi) {
#pragma unroll
            for (int r = 0; r < 4; ++r) {
                int row = mi * 16 + q * 4 + r;
                float f  = fminf(df[row] * (NTAB / 4.0f), NTAB - 1.01f);
                float fi = floorf(f);
                int   i0 = (int)fi;
                float fr = f - fi;
                const unsigned* wrow = wtabI + i0 * 128;
#pragma unroll
                for (int ni = 0; ni < 2; ++ni) {
                    int col = wave * 32 + ni * 16 + c16;
                    unsigned wp = wrow[col];
                    float w0 = __builtin_bit_cast(float, wp << 16);
                    float w1 = __builtin_bit_cast(float, wp & 0xffff0000u);
                    float wv = fmaf(fr, w1 - w0, w0);
                    float g  = (sacc[mi][ni][r] + bs2c[ni]) * wv;
                    LDSu[A2_O + row * ASTR + col] =
                        (unsigned short)(__builtin_bit_cast(unsigned, g) >> 16);
                }
            }
        }
    }
    __syncthreads();   // G ready

    // ---------- head: wave owns 16 edges, all 64 cols; env+atomic fused ----------
    {
        const int rowb = wave * 16;
        floatx4 oacc[4];
#pragma unroll
        for (int ni = 0; ni < 4; ++ni) oacc[ni] = zero4;
#pragma unroll
        for (int kk = 0; kk < 4; ++kk) {
            short8 af = *(const short8*)&LDSu[A2_O + (rowb + c16) * ASTR + kk * 32 + q * 8];
#pragma unroll
            for (int ni = 0; ni < 4; ++ni) {
                short8 bfr = *(const short8*)&wt[WO1_O + (ni * 16 + c16) * 128 + kk * 32 + q * 8];
                oacc[ni] = MFMA16(af, bfr, oacc[ni]);
            }
        }
        float bo1c[4], wo2c[4];
#pragma unroll
        for (int ni = 0; ni < 4; ++ni) {
            bo1c[ni] = b_o1[ni * 16 + c16];
            wo2c[ni] = w_o2[ni * 16 + c16];
        }
        float bo2 = b_o2[0];
#pragma unroll
        for (int r = 0; r < 4; ++r) {
            float s = 0.f;
#pragma unroll
            for (int ni = 0; ni < 4; ++ni)
                s += silu_f(oacc[ni][r] + bo1c[ni]) * wo2c[ni];
            s += __shfl_xor(s, 1); s += __shfl_xor(s, 2);
            s += __shfl_xor(s, 4); s += __shfl_xor(s, 8);
            if (c16 == 0) {
                int row = rowb + q * 4 + r;
                float dd = df[row];
                float x  = dd * 0.25f;
                float x2 = x * x, x4 = x2 * x2;
                float x5 = x4 * x, x6 = x5 * x, x7 = x6 * x;
                float env = 1.0f - 21.0f * x5 + 35.0f * x6 - 15.0f * x7;
                env = (dd < 4.0f) ? env : 0.0f;
                float mw = (s + bo2) * env;
                if (mw != 0.f) unsafeAtomicAdd(&out[probe_s[row]], mw);
            }
        }
    }
}

extern "C" void kernel_launch(void* const* d_in, const int* in_sizes, int n_in,
                              void* d_out, int out_size, void* d_ws, size_t ws_size,
                              hipStream_t stream) {
    const float* diff    = (const float*)d_in[0];
    const float* S_JK    = (const float*)d_in[1];
    const float* V_JK    = (const float*)d_in[2];
    const int*   atom_i  = (const int*)d_in[3];
    const int*   probe_i = (const int*)d_in[4];
    const float* w_s1 = (const float*)d_in[6];
    const float* b_s1 = (const float*)d_in[7];
    const float* g_ln = (const float*)d_in[8];
    const float* b_ln = (const float*)d_in[9];
    const float* w_s2 = (const float*)d_in[10];
    const float* b_s2 = (const float*)d_in[11];
    const float* w_f1 = (const float*)d_in[12];
    const float* b_f1 = (const float*)d_in[13];
    const float* w_f2 = (const float*)d_in[14];
    const float* b_f2 = (const float*)d_in[15];
    const float* w_o1 = (const float*)d_in[16];
    const float* b_o1 = (const float*)d_in[17];
    const float* w_o2 = (const float*)d_in[18];
    const float* b_o2 = (const float*)d_in[19];
    const float* fbias = (const float*)d_in[20];
    float* out = (float*)d_out;

    char* ws = (char*)d_ws;
    unsigned short* wt    = (unsigned short*)ws;
    unsigned short* pqp   = (unsigned short*)(ws + PQ_B);
    unsigned*       wtabI = (unsigned*)(ws + WTI_B);

    cfr_prep1<<<LIN1B + TABB, 256, 0, stream>>>(w_s1, w_s2, w_o1, w_f1, b_f1, w_f2, b_f2,
                                                fbias, out, wt, wtabI);
    cfr_prep2<<<(N_ATOMS + 31) / 32, 256, 0, stream>>>(S_JK, V_JK, b_s1, wt, pqp);
    cfr_main<<<E_TOTAL / EPB, 256, 0, stream>>>(diff, atom_i, probe_i, wt, pqp, wtabI,
        g_ln, b_ln, b_s2, b_o1, w_o2, b_o2, out);
}

// Round 9
// 247.970 us; speedup vs baseline: 1.2402x; 1.2011x over previous
//
#include <hip/hip_runtime.h>

#define EPB     64
#define E_TOTAL 262144
#define NPROBE  100000
#define N_ATOMS 20000
#define NTAB    2048         // lerp intervals over dist in [0,4)

// LDS layout (main): A2/G region 17,408 B + df/probe 512 B
#define ASTR   136           // row stride shorts: 272 B = 16 B * 17 -> 2-way (free) banks
#define A2_O   0
#define LDS_SH 8704

// workspace layout (byte offsets)
#define WS1_O  0             // shorts: w_s1^T bf16 128x384
#define WS2_O  49152         // shorts: w_s2^T bf16 128x128
#define WO1_O  65536         // shorts: w_o1^T bf16 64x128
#define WT_TOT 73728         // shorts
#define PQ_B   147456        // PQ[a][512] bf16 (20.48 MB)
#define WTI_B  20627456      // uint wtabI[NTAB][128] interleaved bf16 pairs (1.0 MB)
// total ~21.7 MB

// prep1 block ranges
#define L_WT_OFF   NPROBE                   // 100000
#define L_TOT      (NPROBE + WT_TOT)        // 173728
#define LIN1B      ((L_TOT + 255) / 256)    // 679
#define TABB       ((NTAB + 2) / 2)         // 1025 blocks, 2 rows each (rows 0..NTAB)

typedef __attribute__((ext_vector_type(8))) short          short8;
typedef __attribute__((ext_vector_type(8))) unsigned short ushort8;
typedef __attribute__((ext_vector_type(4))) float          floatx4;

#define MFMA16(a, b, c) __builtin_amdgcn_mfma_f32_16x16x32_bf16((a), (b), (c), 0, 0, 0)

__device__ __forceinline__ unsigned short f2bfu(float x) {   // RNE
    unsigned u = __builtin_bit_cast(unsigned, x);
    u = (u + 0x7FFFu + ((u >> 16) & 1u)) >> 16;
    return (unsigned short)u;
}
__device__ __forceinline__ unsigned pk2(float lo, float hi) {   // {bf16(hi)|bf16(lo)} trunc
    return __builtin_amdgcn_perm(__builtin_bit_cast(unsigned, hi),
                                 __builtin_bit_cast(unsigned, lo), 0x07060302u);
}
__device__ __forceinline__ float bf2f(unsigned short u) {
    return __builtin_bit_cast(float, ((unsigned)u) << 16);
}
__device__ __forceinline__ float silu_f(float x) { return x / (1.0f + __expf(-x)); }

struct F8 { float v[8]; };
__device__ __forceinline__ F8 ld8(const float* __restrict__ p) {
    F8 r;
    const float4 a = *(const float4*)p;
    const float4 b = *(const float4*)(p + 4);
    r.v[0] = a.x; r.v[1] = a.y; r.v[2] = a.z; r.v[3] = a.w;
    r.v[4] = b.x; r.v[5] = b.y; r.v[6] = b.z; r.v[7] = b.w;
    return r;
}

// ---------- prep1: out-init + wt transpose + W-table (interleaved via dual 16-bit stores) ----------
__global__ __launch_bounds__(256) void cfr_prep1(
    const float* __restrict__ w_s1, const float* __restrict__ w_s2,
    const float* __restrict__ w_o1,
    const float* __restrict__ w_f1, const float* __restrict__ b_f1,
    const float* __restrict__ w_f2, const float* __restrict__ b_f2,
    const float* __restrict__ fb, float* __restrict__ out,
    unsigned short* __restrict__ wt, unsigned* __restrict__ wtabI)
{
    __shared__ float ep[2][32];
    __shared__ float f1s[2][128];
    const int t = threadIdx.x;

    if (blockIdx.x < LIN1B) {
        int i = blockIdx.x * 256 + t;
        if (i < NPROBE) {
            out[i] = fb[0];
        } else if (i < L_TOT) {
            int j = i - L_WT_OFF;
            float v;
            if (j < WS2_O)      { int n = j / 384, k = j - n * 384;           v = w_s1[k * 128 + n]; }
            else if (j < WO1_O) { int m = j - WS2_O, n = m >> 7, k = m & 127; v = w_s2[k * 128 + n]; }
            else                { int m = j - WO1_O, n = m >> 7, k = m & 127; v = w_o1[k * 64 + n]; }
            wt[j] = f2bfu(v);
        }
        return;
    }

    const int half = t >> 7;
    const int c    = t & 127;
    const int r    = (blockIdx.x - LIN1B) * 2 + half;    // 0..NTAB (+1 spare, guarded)
    float d = fmaxf(r * (4.0f / NTAB), 1e-4f);
    if (c < 32) ep[half][c] = sinf(d * (c + 1) * 0.7853981633974483f) / d;
    __syncthreads();
    float f1 = b_f1[c];
#pragma unroll
    for (int k = 0; k < 32; ++k) f1 = fmaf(ep[half][k], w_f1[k * 128 + c], f1);
    f1s[half][c] = silu_f(f1);
    __syncthreads();
    if (r > NTAB) return;
    float w = b_f2[c];
#pragma unroll 4
    for (int k = 0; k < 128; ++k) w = fmaf(f1s[half][k], w_f2[k * 128 + c], w);
    unsigned short wb = f2bfu(w);
    unsigned short* wtabH = (unsigned short*)wtabI;
    if (r < NTAB) wtabH[(r * 128 + c) * 2] = wb;             // lo half of wtabI[r][c]
    if (r >= 1)   wtabH[((r - 1) * 128 + c) * 2 + 1] = wb;   // hi half of wtabI[r-1][c]
}

// ---------- prep2: per-atom P = [S|n]@w_s1[0:256] + b_s1 and Q_d = V_d@w_s1[256:384] ----------
__global__ __launch_bounds__(256, 3) void cfr_prep2(
    const float* __restrict__ S, const float* __restrict__ V,
    const float* __restrict__ b_s1,
    const unsigned short* __restrict__ wt, unsigned short* __restrict__ pq)
{
    __shared__ __align__(16) unsigned short bufH[32 * 264];
    __shared__ __align__(16) unsigned short bufV[96 * 136];

    const int t    = threadIdx.x;
    const int a0   = blockIdx.x * 32;
    const int wave = t >> 6;
    const int lane = t & 63;
    const int q    = lane >> 4;
    const int c16  = lane & 15;

#pragma unroll
    for (int it = 0; it < 2; ++it) {
        int idx = it * 256 + t;
        int al = idx >> 4, f8 = (idx & 15) * 8;
        int a = a0 + al;
        ushort8 sS, sN, s0, s1, s2;
        if (a < N_ATOMS) {
            F8 s  = ld8(S + a * 128 + f8);
            F8 v0 = ld8(V + a * 384 + f8);
            F8 v1 = ld8(V + a * 384 + 128 + f8);
            F8 v2 = ld8(V + a * 384 + 256 + f8);
#pragma unroll
            for (int j = 0; j < 8; ++j) {
                sS[j] = f2bfu(s.v[j]);
                sN[j] = f2bfu(sqrtf(v0.v[j]*v0.v[j] + v1.v[j]*v1.v[j] + v2.v[j]*v2.v[j] + 1e-8f));
                s0[j] = f2bfu(v0.v[j]);
                s1[j] = f2bfu(v1.v[j]);
                s2[j] = f2bfu(v2.v[j]);
            }
        } else {
#pragma unroll
            for (int j = 0; j < 8; ++j) { sS[j]=0; sN[j]=0; s0[j]=0; s1[j]=0; s2[j]=0; }
        }
        *(ushort8*)&bufH[al * 264 + f8]        = sS;
        *(ushort8*)&bufH[al * 264 + 128 + f8]  = sN;
        *(ushort8*)&bufV[al * 136 + f8]        = s0;
        *(ushort8*)&bufV[(32 + al) * 136 + f8] = s1;
        *(ushort8*)&bufV[(64 + al) * 136 + f8] = s2;
    }
    __syncthreads();

    const floatx4 zero4 = {0.f, 0.f, 0.f, 0.f};
    float bs1c[2];
#pragma unroll
    for (int ni = 0; ni < 2; ++ni) bs1c[ni] = b_s1[wave * 32 + ni * 16 + c16];

    {   // P
        floatx4 pacc[2][2];
#pragma unroll
        for (int mi = 0; mi < 2; ++mi) { pacc[mi][0] = zero4; pacc[mi][1] = zero4; }
#pragma unroll
        for (int kk = 0; kk < 8; ++kk) {
            short8 bfr[2], af[2];
#pragma unroll
            for (int ni = 0; ni < 2; ++ni) {
                int n = wave * 32 + ni * 16 + c16;
                bfr[ni] = *(const short8*)&wt[WS1_O + n * 384 + kk * 32 + q * 8];
            }
#pragma unroll
            for (int mi = 0; mi < 2; ++mi)
                af[mi] = *(const short8*)&bufH[(mi * 16 + c16) * 264 + kk * 32 + q * 8];
#pragma unroll
            for (int mi = 0; mi < 2; ++mi)
#pragma unroll
                for (int ni = 0; ni < 2; ++ni)
                    pacc[mi][ni] = MFMA16(af[mi], bfr[ni], pacc[mi][ni]);
        }
#pragma unroll
        for (int mi = 0; mi < 2; ++mi)
#pragma unroll
            for (int r = 0; r < 4; ++r) {
                int a = a0 + mi * 16 + q * 4 + r;
                if (a < N_ATOMS)
#pragma unroll
                    for (int ni = 0; ni < 2; ++ni) {
                        int col = wave * 32 + ni * 16 + c16;
                        pq[a * 512 + col] = f2bfu(pacc[mi][ni][r] + bs1c[ni]);
                    }
            }
    }

    short8 bq[4][2];
#pragma unroll
    for (int kk = 0; kk < 4; ++kk)
#pragma unroll
        for (int ni = 0; ni < 2; ++ni) {
            int n = wave * 32 + ni * 16 + c16;
            bq[kk][ni] = *(const short8*)&wt[WS1_O + n * 384 + 256 + kk * 32 + q * 8];
        }
#pragma unroll
    for (int d = 0; d < 3; ++d) {
        floatx4 qacc[2][2];
#pragma unroll
        for (int mi = 0; mi < 2; ++mi) { qacc[mi][0] = zero4; qacc[mi][1] = zero4; }
#pragma unroll
        for (int kk = 0; kk < 4; ++kk) {
            short8 af[2];
#pragma unroll
            for (int mi = 0; mi < 2; ++mi)
                af[mi] = *(const short8*)&bufV[(d * 32 + mi * 16 + c16) * 136 + kk * 32 + q * 8];
#pragma unroll
            for (int mi = 0; mi < 2; ++mi)
#pragma unroll
                for (int ni = 0; ni < 2; ++ni)
                    qacc[mi][ni] = MFMA16(af[mi], bq[kk][ni], qacc[mi][ni]);
        }
#pragma unroll
        for (int mi = 0; mi < 2; ++mi)
#pragma unroll
            for (int r = 0; r < 4; ++r) {
                int a = a0 + mi * 16 + q * 4 + r;
                if (a < N_ATOMS)
#pragma unroll
                    for (int ni = 0; ni < 2; ++ni) {
                        int col = wave * 32 + ni * 16 + c16;
                        pq[a * 512 + (1 + d) * 128 + col] = f2bfu(qacc[mi][ni][r]);
                    }
            }
    }
}

// __launch_bounds__(256,4): 128 VGPR budget — (256,8) capped VGPRs at 32 and
// spilled u[32] to scratch (R8: WRITE_SIZE 224 MB, main 165 us). Do not raise.
__global__ __launch_bounds__(256, 4) void cfr_main(
    const float* __restrict__ diff,
    const int* __restrict__ atom_idx, const int* __restrict__ probe_idx,
    const unsigned short* __restrict__ wt, const unsigned short* __restrict__ pq,
    const unsigned* __restrict__ wtabI,
    const float* __restrict__ g_ln, const float* __restrict__ b_ln,
    const float* __restrict__ b_s2, const float* __restrict__ b_o1,
    const float* __restrict__ w_o2, const float* __restrict__ b_o2,
    float* __restrict__ out)
{
    __shared__ __align__(16) unsigned short LDSu[LDS_SH];   // A2, then G
    __shared__ float df[EPB];
    __shared__ int   probe_s[EPB];

    const int t    = threadIdx.x;
    const int e0   = blockIdx.x * EPB;
    const int wave = t >> 6;
    const int lane = t & 63;
    const int q    = lane >> 4;
    const int c16  = lane & 15;
    const floatx4 zero4 = {0.f, 0.f, 0.f, 0.f};

    const int el = t >> 2;
    const int c0 = (t & 3) * 32;

    // ---------- phase 1: U = P + r.Q -> LN -> SiLU -> A2 ----------
    {
        const int eg = e0 + el;
        const int a  = atom_idx[eg];
        float dx = diff[eg * 3 + 0], dy = diff[eg * 3 + 1], dz = diff[eg * 3 + 2];
        float sq = dx * dx + dy * dy + dz * dz;
        float dist = sqrtf(sq);
        float rinv = rsqrtf(sq + 1e-8f);
        float rx = dx * rinv, ry = dy * rinv, rz = dz * rinv;
        if ((t & 3) == 0) { df[el] = dist; probe_s[el] = probe_idx[eg]; }

        const ushort8* pqr = (const ushort8*)(pq + a * 512 + c0);
        float u[32];
#pragma unroll
        for (int g = 0; g < 4; ++g) {
            ushort8 v = pqr[g];            // P
#pragma unroll
            for (int j = 0; j < 8; ++j) u[g * 8 + j] = bf2f(v[j]);
        }
#pragma unroll
        for (int g = 0; g < 4; ++g) {
            ushort8 v = pqr[16 + g];       // Q0
#pragma unroll
            for (int j = 0; j < 8; ++j) u[g * 8 + j] = fmaf(bf2f(v[j]), rx, u[g * 8 + j]);
        }
#pragma unroll
        for (int g = 0; g < 4; ++g) {
            ushort8 v = pqr[32 + g];       // Q1
#pragma unroll
            for (int j = 0; j < 8; ++j) u[g * 8 + j] = fmaf(bf2f(v[j]), ry, u[g * 8 + j]);
        }
#pragma unroll
        for (int g = 0; g < 4; ++g) {
            ushort8 v = pqr[48 + g];       // Q2
#pragma unroll
            for (int j = 0; j < 8; ++j) u[g * 8 + j] = fmaf(bf2f(v[j]), rz, u[g * 8 + j]);
        }
        float s = 0.f, s2 = 0.f;
#pragma unroll
        for (int j = 0; j < 32; ++j) { s += u[j]; s2 = fmaf(u[j], u[j], s2); }
        s  += __shfl_xor(s, 1);  s  += __shfl_xor(s, 2);
        s2 += __shfl_xor(s2, 1); s2 += __shfl_xor(s2, 2);
        float mu = s * (1.f / 128.f);
        float rstd = rsqrtf(s2 * (1.f / 128.f) - mu * mu + 1e-5f);
        const float4* gp = (const float4*)(g_ln + c0);
        const float4* bp = (const float4*)(b_ln + c0);
        unsigned pko[16];
#pragma unroll
        for (int g4 = 0; g4 < 8; ++g4) {
            float4 gg = gp[g4], bb = bp[g4];
            float y0 = silu_f((u[g4 * 4 + 0] - mu) * rstd * gg.x + bb.x);
            float y1 = silu_f((u[g4 * 4 + 1] - mu) * rstd * gg.y + bb.y);
            float y2 = silu_f((u[g4 * 4 + 2] - mu) * rstd * gg.z + bb.z);
            float y3 = silu_f((u[g4 * 4 + 3] - mu) * rstd * gg.w + bb.w);
            pko[g4 * 2 + 0] = pk2(y0, y1);
            pko[g4 * 2 + 1] = pk2(y2, y3);
        }
        uint4* dst = (uint4*)&LDSu[A2_O + el * ASTR + c0];
        dst[0] = make_uint4(pko[0], pko[1], pko[2], pko[3]);
        dst[1] = make_uint4(pko[4], pko[5], pko[6], pko[7]);
        dst[2] = make_uint4(pko[8], pko[9], pko[10], pko[11]);
        dst[3] = make_uint4(pko[12], pko[13], pko[14], pko[15]);
    }
    __syncthreads();   // A2 ready

    // ---------- mm2: S = A2 @ w_s2 + b_s2, then G = S ⊙ W(dist) in C-layout ----------
    {
        floatx4 sacc[4][2];
#pragma unroll
        for (int mi = 0; mi < 4; ++mi) { sacc[mi][0] = zero4; sacc[mi][1] = zero4; }
#pragma unroll
        for (int kk = 0; kk < 4; ++kk) {
            short8 a2f[4], b2[2];
#pragma unroll
            for (int ni = 0; ni < 2; ++ni) {
                int n = wave * 32 + ni * 16 + c16;
                b2[ni] = *(const short8*)&wt[WS2_O + n * 128 + kk * 32 + q * 8];
            }
#pragma unroll
            for (int mi = 0; mi < 4; ++mi)
                a2f[mi] = *(const short8*)&LDSu[A2_O + (mi * 16 + c16) * ASTR + kk * 32 + q * 8];
#pragma unroll
            for (int mi = 0; mi < 4; ++mi)
#pragma unroll
                for (int ni = 0; ni < 2; ++ni)
                    sacc[mi][ni] = MFMA16(a2f[mi], b2[ni], sacc[mi][ni]);
        }
        __syncthreads();   // all A2 reads done; region becomes G

        float bs2c[2];
#pragma unroll
        for (int ni = 0; ni < 2; ++ni) bs2c[ni] = b_s2[wave * 32 + ni * 16 + c16];
#pragma unroll
        for (int mi = 0; mi < 4; ++mi) {
#pragma unroll
            for (int r = 0; r < 4; ++r) {
                int row = mi * 16 + q * 4 + r;
                float f  = fminf(df[row] * (NTAB / 4.0f), NTAB - 1.01f);
                float fi = floorf(f);
                int   i0 = (int)fi;
                float fr = f - fi;
                const unsigned* wrow = wtabI + i0 * 128;
#pragma unroll
                for (int ni = 0; ni < 2; ++ni) {
                    int col = wave * 32 + ni * 16 + c16;
                    unsigned wp = wrow[col];
                    float w0 = __builtin_bit_cast(float, wp << 16);
                    float w1 = __builtin_bit_cast(float, wp & 0xffff0000u);
                    float wv = fmaf(fr, w1 - w0, w0);
                    float g  = (sacc[mi][ni][r] + bs2c[ni]) * wv;
                    LDSu[A2_O + row * ASTR + col] =
                        (unsigned short)(__builtin_bit_cast(unsigned, g) >> 16);
                }
            }
        }
    }
    __syncthreads();   // G ready

    // ---------- head: wave owns 16 edges, all 64 cols; env+atomic fused ----------
    {
        const int rowb = wave * 16;
        floatx4 oacc[4];
#pragma unroll
        for (int ni = 0; ni < 4; ++ni) oacc[ni] = zero4;
#pragma unroll
        for (int kk = 0; kk < 4; ++kk) {
            short8 af = *(const short8*)&LDSu[A2_O + (rowb + c16) * ASTR + kk * 32 + q * 8];
#pragma unroll
            for (int ni = 0; ni < 4; ++ni) {
                short8 bfr = *(const short8*)&wt[WO1_O + (ni * 16 + c16) * 128 + kk * 32 + q * 8];
                oacc[ni] = MFMA16(af, bfr, oacc[ni]);
            }
        }
        float bo1c[4], wo2c[4];
#pragma unroll
        for (int ni = 0; ni < 4; ++ni) {
            bo1c[ni] = b_o1[ni * 16 + c16];
            wo2c[ni] = w_o2[ni * 16 + c16];
        }
        float bo2 = b_o2[0];
#pragma unroll
        for (int r = 0; r < 4; ++r) {
            float s = 0.f;
#pragma unroll
            for (int ni = 0; ni < 4; ++ni)
                s += silu_f(oacc[ni][r] + bo1c[ni]) * wo2c[ni];
            s += __shfl_xor(s, 1); s += __shfl_xor(s, 2);
            s += __shfl_xor(s, 4); s += __shfl_xor(s, 8);
            if (c16 == 0) {
                int row = rowb + q * 4 + r;
                float dd = df[row];
                float x  = dd * 0.25f;
                float x2 = x * x, x4 = x2 * x2;
                float x5 = x4 * x, x6 = x5 * x, x7 = x6 * x;
                float env = 1.0f - 21.0f * x5 + 35.0f * x6 - 15.0f * x7;
                env = (dd < 4.0f) ? env : 0.0f;
                float mw = (s + bo2) * env;
                if (mw != 0.f) unsafeAtomicAdd(&out[probe_s[row]], mw);
            }
        }
    }
}

extern "C" void kernel_launch(void* const* d_in, const int* in_sizes, int n_in,
                              void* d_out, int out_size, void* d_ws, size_t ws_size,
                              hipStream_t stream) {
    const float* diff    = (const float*)d_in[0];
    const float* S_JK    = (const float*)d_in[1];
    const float* V_JK    = (const float*)d_in[2];
    const int*   atom_i  = (const int*)d_in[3];
    const int*   probe_i = (const int*)d_in[4];
    const float* w_s1 = (const float*)d_in[6];
    const float* b_s1 = (const float*)d_in[7];
    const float* g_ln = (const float*)d_in[8];
    const float* b_ln = (const float*)d_in[9];
    const float* w_s2 = (const float*)d_in[10];
    const float* b_s2 = (const float*)d_in[11];
    const float* w_f1 = (const float*)d_in[12];
    const float* b_f1 = (const float*)d_in[13];
    const float* w_f2 = (const float*)d_in[14];
    const float* b_f2 = (const float*)d_in[15];
    const float* w_o1 = (const float*)d_in[16];
    const float* b_o1 = (const float*)d_in[17];
    const float* w_o2 = (const float*)d_in[18];
    const float* b_o2 = (const float*)d_in[19];
    const float* fbias = (const float*)d_in[20];
    float* out = (float*)d_out;

    char* ws = (char*)d_ws;
    unsigned short* wt    = (unsigned short*)ws;
    unsigned short* pqp   = (unsigned short*)(ws + PQ_B);
    unsigned*       wtabI = (unsigned*)(ws + WTI_B);

    cfr_prep1<<<LIN1B + TABB, 256, 0, stream>>>(w_s1, w_s2, w_o1, w_f1, b_f1, w_f2, b_f2,
                                                fbias, out, wt, wtabI);
    cfr_prep2<<<(N_ATOMS + 31) / 32, 256, 0, stream>>>(S_JK, V_JK, b_s1, wt, pqp);
    cfr_main<<<E_TOTAL / EPB, 256, 0, stream>>>(diff, atom_i, probe_i, wt, pqp, wtabI,
        g_ln, b_ln, b_s2, b_o1, w_o2, b_o2, out);
}